// Round 9
// baseline (320.712 us; speedup 1.0000x reference)
//
#include <hip/hip_runtime.h>
#include <stdint.h>

#define Bdim 32
#define Tdim 12
#define Vdim 1024
#define Edim 64
#define Gdim 32
#define BT   384   // B*T

typedef __attribute__((ext_vector_type(8))) short bf16x8;
typedef __attribute__((ext_vector_type(4))) float f32x4;

// pk2(a,b): bf16(a) in low 16, bf16(b) in high 16 — single HW instr, RNE.
__device__ __forceinline__ uint pk2(float a, float b) {
    uint r;
    asm("v_cvt_pk_bf16_f32 %0, %1, %2" : "=v"(r) : "v"(a), "v"(b));
    return r;
}
__device__ __forceinline__ ushort f2bf(float f) {
    return (ushort)(pk2(f, f) & 0xffffu);
}

// ---------------------------------------------------------------------------
// K1a: Xbf[e][bt][i] (bf16) = inputs[bt][i][e] (f32)
// ---------------------------------------------------------------------------
__global__ __launch_bounds__(256) void k_xpose(const float* __restrict__ in,
                                               ushort* __restrict__ Xbf) {
    __shared__ float tile[64][68];
    const int bt = blockIdx.x >> 4;
    const int i0 = (blockIdx.x & 15) << 6;
    const int r  = threadIdx.x >> 2;     // i-local on load, e on store
    const int q  = threadIdx.x & 3;
    const float* src = in + ((size_t)(bt * Vdim) + i0 + r) * Edim + q * 16;
#pragma unroll
    for (int k = 0; k < 4; ++k)
        *(float4*)&tile[r][q * 16 + 4 * k] = *(const float4*)(src + 4 * k);
    __syncthreads();
    const int e  = r;
    const int ib = q * 16;
    uint4 s0, s1;
    s0.x = pk2(tile[ib + 0][e],  tile[ib + 1][e]);
    s0.y = pk2(tile[ib + 2][e],  tile[ib + 3][e]);
    s0.z = pk2(tile[ib + 4][e],  tile[ib + 5][e]);
    s0.w = pk2(tile[ib + 6][e],  tile[ib + 7][e]);
    s1.x = pk2(tile[ib + 8][e],  tile[ib + 9][e]);
    s1.y = pk2(tile[ib + 10][e], tile[ib + 11][e]);
    s1.z = pk2(tile[ib + 12][e], tile[ib + 13][e]);
    s1.w = pk2(tile[ib + 14][e], tile[ib + 15][e]);
    ushort* dst = Xbf + ((size_t)(e * BT) + bt) * Vdim + i0 + ib;
    *(uint4*)dst = s0;
    *(uint4*)(dst + 8) = s1;
}

// ---------------------------------------------------------------------------
// K1b: Se[e][v][g] (bf16) = srpe[v][g][e] (f32)
// ---------------------------------------------------------------------------
__global__ __launch_bounds__(256) void k_se(const float* __restrict__ srpe,
                                            ushort* __restrict__ Se) {
    __shared__ float t2[256][65];        // [vv*32+g][e], pad 65
    const int tid = threadIdx.x;
    const int v0 = blockIdx.x * 8;
#pragma unroll
    for (int c = 0; c < 16; ++c) {
        int f = (c * 256 + tid) * 4;     // flat f32 idx within block slab
        int vg = f >> 6;
        int e4 = f & 63;
        *(float4*)&t2[vg][e4] = *(const float4*)(srpe + (size_t)v0 * Gdim * Edim + f);
    }
    __syncthreads();
    const int e = tid & 63;
#pragma unroll
    for (int h = 0; h < 2; ++h) {
        const int vv = (tid >> 6) * 2 + h;
        uint4 o[2];
#pragma unroll
        for (int c = 0; c < 2; ++c) {
            o[c].x = pk2(t2[vv * 32 + c * 16 + 0][e],  t2[vv * 32 + c * 16 + 1][e]);
            o[c].y = pk2(t2[vv * 32 + c * 16 + 2][e],  t2[vv * 32 + c * 16 + 3][e]);
            o[c].z = pk2(t2[vv * 32 + c * 16 + 4][e],  t2[vv * 32 + c * 16 + 5][e]);
            o[c].w = pk2(t2[vv * 32 + c * 16 + 6][e],  t2[vv * 32 + c * 16 + 7][e]);
        }
        uint4 o2[2];
#pragma unroll
        for (int c = 0; c < 2; ++c) {
            o2[c].x = pk2(t2[vv * 32 + c * 16 + 8][e],  t2[vv * 32 + c * 16 + 9][e]);
            o2[c].y = pk2(t2[vv * 32 + c * 16 + 10][e], t2[vv * 32 + c * 16 + 11][e]);
            o2[c].z = pk2(t2[vv * 32 + c * 16 + 12][e], t2[vv * 32 + c * 16 + 13][e]);
            o2[c].w = pk2(t2[vv * 32 + c * 16 + 14][e], t2[vv * 32 + c * 16 + 15][e]);
        }
        ushort* dst = Se + ((size_t)(e * Vdim) + v0 + vv) * Gdim;
        *(uint4*)(dst + 0)  = o[0];
        *(uint4*)(dst + 8)  = o2[0];
        *(uint4*)(dst + 16) = o[1];
        *(uint4*)(dst + 24) = o2[1];
    }
}

// ---------------------------------------------------------------------------
// K2: MFMA graph-mix, depth-2 counted-vmcnt pipeline (unchanged).
// ---------------------------------------------------------------------------
__global__ __launch_bounds__(256, 2) void k_relmix_mfma(const ushort* __restrict__ Xbf,
                                                        const ushort* __restrict__ Se,
                                                        ushort* __restrict__ xrel) {
    __shared__ __align__(16) ushort A_s[3][192 * 32];   // [bt][i], src-swizzled
    __shared__ __align__(16) ushort Si_s[3][32 * 32];   // [i][g],  src-swizzled
    __shared__ __align__(16) ushort R_s[2][128 * 40];   // [v][i],  80 B pitch

    const int tid = threadIdx.x;
    const int l = tid & 63;
    const int w = tid >> 6;              // wave 0..3
    const int wm = w >> 1;               // bt half (96 each)
    const int wn = w & 1;                // v half (64 each)

    const int raw = blockIdx.x;                       // 0..1023
    const int wg  = (raw & 7) * 128 + (raw >> 3);     // bijective
    const int e   = wg >> 4;
    const int btT = (wg >> 3) & 1;
    const int vT  = wg & 7;
    const int bt0 = btT * 192;
    const int v0  = vT * 128;

    const int lr  = l >> 2;                           // sub-row in 16-row chunk
    const int lc  = ((l & 3) ^ (lr & 3)) * 8;         // swizzled col (ushort)

    const ushort* gA  = Xbf + ((size_t)(e * BT + bt0)) * Vdim;
    const ushort* gSi = Se + (size_t)e * Vdim * Gdim;

    bf16x8 svF[2];
    {
        const ushort* gSv = Se + ((size_t)e * Vdim + v0) * Gdim;
#pragma unroll
        for (int k = 0; k < 2; ++k) {
            const int vloc = (2 * w + k) * 16 + (l & 15);
            svF[k] = *(const bf16x8*)(gSv + (size_t)vloc * Gdim + (l >> 4) * 8);
        }
    }
    __builtin_amdgcn_sched_barrier(0);

    if (w < 2)
        __builtin_amdgcn_global_load_lds(gSi + (size_t)(0 + w * 16 + lr) * Gdim + lc,
                                         &Si_s[0][w * 512], 16, 0, 0);
#pragma unroll
    for (int c = 0; c < 3; ++c) {
        int chunk = w * 3 + c;
        __builtin_amdgcn_global_load_lds(gA + (size_t)(chunk * 16 + lr) * Vdim + 0 + lc,
                                         &A_s[0][chunk * 512], 16, 0, 0);
    }
    if (w < 2)
        __builtin_amdgcn_global_load_lds(gSi + (size_t)(32 + w * 16 + lr) * Gdim + lc,
                                         &Si_s[1][w * 512], 16, 0, 0);
#pragma unroll
    for (int c = 0; c < 3; ++c) {
        int chunk = w * 3 + c;
        __builtin_amdgcn_global_load_lds(gA + (size_t)(chunk * 16 + lr) * Vdim + 32 + lc,
                                         &A_s[1][chunk * 512], 16, 0, 0);
    }
    asm volatile("s_waitcnt vmcnt(3)" ::: "memory");
    __builtin_amdgcn_sched_barrier(0);
    __builtin_amdgcn_s_barrier();
    __builtin_amdgcn_sched_barrier(0);

    const f32x4 fz = {0.f, 0.f, 0.f, 0.f};

    auto computeR = [&](int sb, int rb) {
        const int r0 = (l & 15), r1 = 16 + (l & 15);
        const int kg = l >> 4;
        bf16x8 siF0 = *(const bf16x8*)&Si_s[sb][r0 * 32 + (kg ^ (r0 & 3)) * 8];
        bf16x8 siF1 = *(const bf16x8*)&Si_s[sb][r1 * 32 + (kg ^ (r1 & 3)) * 8];
#pragma unroll
        for (int k = 0; k < 2; ++k) {
            const int vloc = (2 * w + k) * 16 + (l & 15);
            f32x4 d0 = __builtin_amdgcn_mfma_f32_16x16x32_bf16(siF0, svF[k], fz, 0, 0, 0);
            f32x4 d1 = __builtin_amdgcn_mfma_f32_16x16x32_bf16(siF1, svF[k], fz, 0, 0, 0);
            uint2 w0, w1;
            w0.x = pk2(fmaxf(d0[0], 0.f), fmaxf(d0[1], 0.f));
            w0.y = pk2(fmaxf(d0[2], 0.f), fmaxf(d0[3], 0.f));
            w1.x = pk2(fmaxf(d1[0], 0.f), fmaxf(d1[1], 0.f));
            w1.y = pk2(fmaxf(d1[2], 0.f), fmaxf(d1[3], 0.f));
            *(uint2*)&R_s[rb][vloc * 40 + kg * 4]      = w0;
            *(uint2*)&R_s[rb][vloc * 40 + 16 + kg * 4] = w1;
        }
    };

    computeR(0, 0);
    asm volatile("s_waitcnt lgkmcnt(0)" ::: "memory");
    __builtin_amdgcn_sched_barrier(0);
    __builtin_amdgcn_s_barrier();
    __builtin_amdgcn_sched_barrier(0);

    f32x4 acc[6][4];
#pragma unroll
    for (int m = 0; m < 6; ++m)
#pragma unroll
        for (int n = 0; n < 4; ++n) acc[m][n] = fz;

    int c0 = 0, c1 = 1, c2 = 2;
    int rc = 0, rn = 1;

    for (int t = 0; t < 32; ++t) {
        const int i0f = ((t + 2) & 31) * 32;
        if (w < 2)
            __builtin_amdgcn_global_load_lds(gSi + (size_t)(i0f + w * 16 + lr) * Gdim + lc,
                                             &Si_s[c2][w * 512], 16, 0, 0);
#pragma unroll
        for (int c = 0; c < 3; ++c) {
            int chunk = w * 3 + c;
            __builtin_amdgcn_global_load_lds(gA + (size_t)(chunk * 16 + lr) * Vdim + i0f + lc,
                                             &A_s[c2][chunk * 512], 16, 0, 0);
        }
        computeR(c1, rn);
        bf16x8 aF[6];
#pragma unroll
        for (int m = 0; m < 6; ++m) {
            const int row = wm * 96 + m * 16 + (l & 15);
            aF[m] = *(const bf16x8*)&A_s[c0][row * 32 + (((l >> 4) ^ (row & 3))) * 8];
        }
        __builtin_amdgcn_s_setprio(1);
#pragma unroll
        for (int n = 0; n < 4; ++n) {
            bf16x8 bF = *(const bf16x8*)&R_s[rc][(wn * 64 + n * 16 + (l & 15)) * 40 + (l >> 4) * 8];
#pragma unroll
            for (int m = 0; m < 6; ++m)
                acc[m][n] = __builtin_amdgcn_mfma_f32_16x16x32_bf16(aF[m], bF, acc[m][n], 0, 0, 0);
        }
        __builtin_amdgcn_s_setprio(0);
        asm volatile("s_waitcnt vmcnt(3) lgkmcnt(0)" ::: "memory");
        __builtin_amdgcn_sched_barrier(0);
        __builtin_amdgcn_s_barrier();
        __builtin_amdgcn_sched_barrier(0);
        int tmp = c0; c0 = c1; c1 = c2; c2 = tmp;
        tmp = rc; rc = rn; rn = tmp;
    }

#pragma unroll
    for (int m = 0; m < 6; ++m) {
        const int btl = bt0 + wm * 96 + m * 16 + (l >> 4) * 4;
#pragma unroll
        for (int j = 0; j < 4; ++j) {
            ushort* row = xrel + ((size_t)(e * BT) + btl + j) * Vdim + v0;
#pragma unroll
            for (int n = 0; n < 4; ++n)
                row[wn * 64 + n * 16 + (l & 15)] = f2bf(acc[m][n][j]);
        }
    }
}

// ---------------------------------------------------------------------------
// K2.5: xrT[bt][v][e] = xrel[e][bt][v]   (bf16 -> bf16, XOR-swizzled LDS)
// ---------------------------------------------------------------------------
__global__ __launch_bounds__(256) void k_xrelT(const ushort* __restrict__ xr,
                                               ushort* __restrict__ xrT) {
    __shared__ uint t[64 * 256];         // word (e, vpair), swizzled
    const int tid = threadIdx.x;
    const int bt = blockIdx.x >> 1;
    const int v0 = (blockIdx.x & 1) * 512;
    {
        const int e = tid >> 2, q = tid & 3;
        const ushort* src = xr + ((size_t)(e * BT) + bt) * Vdim + v0 + q * 128;
#pragma unroll
        for (int c = 0; c < 16; ++c) {
            uint4 x = *(const uint4*)(src + c * 8);
            int p = q * 64 + c * 4;
            int sw = ((e & 3) << 3) ^ ((p >> 6) << 2);
            *(uint4*)&t[e * 256 + (p ^ sw)] = x;
        }
    }
    __syncthreads();
    {
        const int p = tid;               // v-pair 0..255
        uint lw[32], hw[32];
#pragma unroll
        for (int e2 = 0; e2 < 32; ++e2) {
            const int ea = 2 * e2, eb = 2 * e2 + 1;
            uint xa = t[ea * 256 + (p ^ (((ea & 3) << 3) ^ ((p >> 6) << 2)))];
            uint xb = t[eb * 256 + (p ^ (((eb & 3) << 3) ^ ((p >> 6) << 2)))];
            lw[e2] = (xa & 0xffffu) | (xb << 16);
            hw[e2] = (xa >> 16) | (xb & 0xffff0000u);
        }
        ushort* d0 = xrT + ((size_t)(bt * Vdim) + v0 + 2 * p) * Edim;
        ushort* d1 = d0 + Edim;
#pragma unroll
        for (int c = 0; c < 8; ++c) {
            uint4 o; o.x = lw[c*4]; o.y = lw[c*4+1]; o.z = lw[c*4+2]; o.w = lw[c*4+3];
            *(uint4*)(d0 + c * 8) = o;
        }
#pragma unroll
        for (int c = 0; c < 8; ++c) {
            uint4 o; o.x = hw[c*4]; o.y = hw[c*4+1]; o.z = hw[c*4+2]; o.w = hw[c*4+3];
            *(uint4*)(d1 + c * 8) = o;
        }
    }
}

// ---------------------------------------------------------------------------
// K3 v4: PERSISTENT. 768 wgs x 16 consecutive tiles tau=(t,v). W streamed
// contiguously (768 KB/wg) via 3-chunk reg-staged rolling prefetch; raw
// s_barrier + lgkmcnt(0) only (no vmcnt(0) drains in the loop). xs gathers
// for tile k+1 issued mid-tile k (idx one tile ahead). Wt layout/swizzle = R8.
// ---------------------------------------------------------------------------
__global__ __launch_bounds__(256, 3) void k_final(const ushort* __restrict__ xrT,
        const int* __restrict__ n_route, const int* __restrict__ s_week,
        const int* __restrict__ s_day,  const float* __restrict__ sape,
        const float* __restrict__ dow,  const float* __restrict__ tod,
        const float* __restrict__ Wc,   const float* __restrict__ bias,
        float* __restrict__ out) {
    __shared__ __align__(16) uint   Wt[3][64 * 36];   // bf16 [e][72f] words, 3 x 9 KB
    __shared__ __align__(16) ushort xs[32 * 216];     // xl bf16 [b][f], pitch 216

    const int tid = threadIdx.x;
    const int l = tid & 63, w = tid >> 6;
    const int mt  = w >> 1;              // b half
    const int ntb = (w & 1) * 2;         // e quarter base
    const int i16 = tid & 15, j16 = tid >> 4;
    const int colb = i16 * 4;
    const int swW  = (i16 & 3) << 2;     // f-word XOR key on write, = 4*((e>>2)&3)
    const int b8 = tid >> 3, e8 = (tid & 7) * 8;
    const int g4 = l >> 4;
    const int ec0 = ntb * 16 + (l & 15), ec1 = ec0 + 16;
    const int arow = (mt * 16 + (l & 15)) * 216;
    const f32x4 fz = {0.f, 0.f, 0.f, 0.f};

    const int tau0 = blockIdx.x * 16;                 // 768 wgs x 16 tiles
    const float* Wgb = Wc + (size_t)tau0 * (192 * Edim);

    // ---- W prologue: 3 chunks in regs
    float4 wr[3][4];
#pragma unroll
    for (int c = 0; c < 3; ++c)
#pragma unroll
        for (int r = 0; r < 4; ++r)
            wr[c][r] = *(const float4*)(Wgb + (size_t)c * 4096 + (j16 * 4 + r) * Edim + colb);

    // ---- gather state (for "next" tile), bias regs
    uint4 xrR; float4 spR0, spR1, dpR0, dpR1, tpR0, tpR1;
    float blc0, blc1, blN0, blN1;
    int nrN, wdN, ddN;

    // gathers(0) + xs(0) + bias(0)
    {
        const int t0 = tau0 >> 10, v0_ = tau0 & 1023;
        const int bt0_ = b8 * Tdim + t0;
        const int nr0 = n_route[b8 * Vdim + v0_];
        const int wd0 = s_week[bt0_], dd0 = s_day[bt0_];
        xrR = *(const uint4*)(xrT + ((size_t)bt0_ * Vdim + v0_) * Edim + e8);
        const float* sp = sape + ((size_t)nr0 * Tdim + t0) * Edim + e8;
        spR0 = *(const float4*)sp;       spR1 = *(const float4*)(sp + 4);
        const float* dp = dow + ((size_t)wd0 * Vdim + v0_) * Edim + e8;
        dpR0 = *(const float4*)dp;       dpR1 = *(const float4*)(dp + 4);
        const float* tp = tod + ((size_t)dd0 * Vdim + v0_) * Edim + e8;
        tpR0 = *(const float4*)tp;       tpR1 = *(const float4*)(tp + 4);
        blc0 = bias[(size_t)tau0 * Edim + ec0];
        blc1 = bias[(size_t)tau0 * Edim + ec1];
    }
    {   // write xs(0)
        *(uint4*)&xs[b8 * 216 + e8] = xrR;
        uint4 o1, o2;
        o1.x = pk2(spR0.x, spR0.y); o1.y = pk2(spR0.z, spR0.w);
        o1.z = pk2(spR1.x, spR1.y); o1.w = pk2(spR1.z, spR1.w);
        *(uint4*)&xs[b8 * 216 + 64 + e8] = o1;
        o2.x = pk2(dpR0.x + tpR0.x, dpR0.y + tpR0.y);
        o2.y = pk2(dpR0.z + tpR0.z, dpR0.w + tpR0.w);
        o2.z = pk2(dpR1.x + tpR1.x, dpR1.y + tpR1.y);
        o2.w = pk2(dpR1.z + tpR1.z, dpR1.w + tpR1.w);
        *(uint4*)&xs[b8 * 216 + 128 + e8] = o2;
    }
    {   // idx(1)
        const int tau1 = tau0 + 1;
        const int t1 = tau1 >> 10, v1 = tau1 & 1023;
        nrN = n_route[b8 * Vdim + v1];
        wdN = s_week[b8 * Tdim + t1];
        ddN = s_day[b8 * Tdim + t1];
    }
    __syncthreads();   // one-time full barrier: xs(0) visible

    for (int k = 0; k < 16; ++k) {
        const int tau = tau0 + k;
        const int t_ = tau >> 10, v_ = tau & 1023;
        f32x4 acc0 = fz, acc1 = fz;
        bf16x8 aF[6];

#pragma unroll
        for (int c = 0; c < 3; ++c) {
            // ---- wwrite chunk c (compiler waits wr[c] loads here)
#pragma unroll
            for (int kq = 0; kq < 4; ++kq) {
                const int e = colb + kq;
                uint2 o;
                o.x = pk2(((const float*)&wr[c][0])[kq], ((const float*)&wr[c][1])[kq]);
                o.y = pk2(((const float*)&wr[c][2])[kq], ((const float*)&wr[c][3])[kq]);
                *(uint2*)&Wt[c][e * 36 + ((2 * j16) ^ swW)] = o;
            }
            asm volatile("s_waitcnt lgkmcnt(0)" ::: "memory");
            __builtin_amdgcn_sched_barrier(0);
            __builtin_amdgcn_s_barrier();
            __builtin_amdgcn_sched_barrier(0);

            if (c == 0) {   // aF(k): xs written before this barrier
#pragma unroll
                for (int ks = 0; ks < 6; ++ks)
                    aF[ks] = *(const bf16x8*)&xs[arow + ks * 32 + g4 * 8];
            }
            // ---- roll W prefetch (chunk 3k+c+3) into freed regs
            if (3 * k + c + 3 < 48) {
#pragma unroll
                for (int r = 0; r < 4; ++r)
                    wr[c][r] = *(const float4*)(Wgb + (size_t)(3 * k + c + 3) * 4096
                                                + (j16 * 4 + r) * Edim + colb);
            }
            if (c == 1 && k < 15) {
                // ---- gathers for tile k+1 (idx regs loaded one tile ago)
                const int tauN = tau + 1;
                const int tN = tauN >> 10, vN = tauN & 1023;
                const int btN = b8 * Tdim + tN;
                xrR = *(const uint4*)(xrT + ((size_t)btN * Vdim + vN) * Edim + e8);
                const float* sp = sape + ((size_t)nrN * Tdim + tN) * Edim + e8;
                spR0 = *(const float4*)sp;       spR1 = *(const float4*)(sp + 4);
                const float* dp = dow + ((size_t)wdN * Vdim + vN) * Edim + e8;
                dpR0 = *(const float4*)dp;       dpR1 = *(const float4*)(dp + 4);
                const float* tp = tod + ((size_t)ddN * Vdim + vN) * Edim + e8;
                tpR0 = *(const float4*)tp;       tpR1 = *(const float4*)(tp + 4);
                blN0 = bias[(size_t)tauN * Edim + ec0];
                blN1 = bias[(size_t)tauN * Edim + ec1];
                if (k < 14) {   // idx for tile k+2
                    const int tauNN = tau + 2;
                    const int tNN = tauNN >> 10, vNN = tauNN & 1023;
                    nrN = n_route[b8 * Vdim + vNN];
                    wdN = s_week[b8 * Tdim + tNN];
                    ddN = s_day[b8 * Tdim + tNN];
                }
            }
            // ---- compute chunk c (2 ks-steps x 2 e-tiles)
            __builtin_amdgcn_s_setprio(1);
#pragma unroll
            for (int kk = 0; kk < 2; ++kk) {
                const int ks = c * 2 + kk;
#pragma unroll
                for (int ni = 0; ni < 2; ++ni) {
                    const int ecol = ni ? ec1 : ec0;
                    const int swr  = ((ecol >> 2) & 3) << 2;
                    uint4 u = *(const uint4*)&Wt[c][ecol * 36 + 16 * kk + ((4 * g4) ^ swr)];
                    bf16x8 bF;
                    __builtin_memcpy(&bF, &u, 16);
                    if (ni == 0) acc0 = __builtin_amdgcn_mfma_f32_16x16x32_bf16(aF[ks], bF, acc0, 0, 0, 0);
                    else         acc1 = __builtin_amdgcn_mfma_f32_16x16x32_bf16(aF[ks], bF, acc1, 0, 0, 0);
                }
            }
            __builtin_amdgcn_s_setprio(0);
        }

        // ---- epilogue stores for tile k
        const int brow = mt * 16 + g4 * 4;
#pragma unroll
        for (int j = 0; j < 4; ++j) {
            float s0 = acc0[j] + blc0;
            s0 = s0 > 0.f ? s0 : 0.3f * s0;
            out[(size_t)((brow + j) * Tdim + t_) * (Vdim * Edim) + v_ * Edim + ec0] = s0;
            float s1 = acc1[j] + blc1;
            s1 = s1 > 0.f ? s1 : 0.3f * s1;
            out[(size_t)((brow + j) * Tdim + t_) * (Vdim * Edim) + v_ * Edim + ec1] = s1;
        }
        // ---- xs(k+1) write (visible after next tile's c==0 barrier)
        if (k < 15) {
            *(uint4*)&xs[b8 * 216 + e8] = xrR;
            uint4 o1, o2;
            o1.x = pk2(spR0.x, spR0.y); o1.y = pk2(spR0.z, spR0.w);
            o1.z = pk2(spR1.x, spR1.y); o1.w = pk2(spR1.z, spR1.w);
            *(uint4*)&xs[b8 * 216 + 64 + e8] = o1;
            o2.x = pk2(dpR0.x + tpR0.x, dpR0.y + tpR0.y);
            o2.y = pk2(dpR0.z + tpR0.z, dpR0.w + tpR0.w);
            o2.z = pk2(dpR1.x + tpR1.x, dpR1.y + tpR1.y);
            o2.w = pk2(dpR1.z + tpR1.z, dpR1.w + tpR1.w);
            *(uint4*)&xs[b8 * 216 + 128 + e8] = o2;
            blc0 = blN0; blc1 = blN1;
        }
    }
}

// ---------------------------------------------------------------------------
extern "C" void kernel_launch(void* const* d_in, const int* in_sizes, int n_in,
                              void* d_out, int out_size, void* d_ws, size_t ws_size,
                              hipStream_t stream) {
    const float* inputs = (const float*)d_in[0];
    const int*   n_route= (const int*)d_in[1];
    const int*   s_week = (const int*)d_in[2];
    const int*   s_day  = (const int*)d_in[3];
    const float* srpe   = (const float*)d_in[4];
    const float* sape   = (const float*)d_in[5];
    const float* dow    = (const float*)d_in[6];
    const float* tod    = (const float*)d_in[7];
    const float* Wc     = (const float*)d_in[8];
    const float* bias   = (const float*)d_in[9];

    // ws layout: Xbf [0, 48MB) ; Se [48MB, 52MB) ; xrT reuses [0, 48MB) after K2
    ushort* Xbf  = (ushort*)d_ws;
    ushort* Se   = (ushort*)((char*)d_ws + (size_t)Edim * BT * Vdim * 2);
    ushort* xrel = (ushort*)d_out;               // bf16 scratch inside d_out
    ushort* xrT  = (ushort*)d_ws;                // overwrites Xbf (dead after K2)
    float*  out  = (float*)d_out;

    k_xpose<<<dim3(BT * 16), dim3(256), 0, stream>>>(inputs, Xbf);
    k_se<<<dim3(Vdim / 8), dim3(256), 0, stream>>>(srpe, Se);
    k_relmix_mfma<<<dim3(1024), dim3(256), 0, stream>>>(Xbf, Se, xrel);
    k_xrelT<<<dim3(BT * 2), dim3(256), 0, stream>>>(xrel, xrT);
    k_final<<<dim3(768), dim3(256), 0, stream>>>(
        xrT, n_route, s_week, s_day, sape, dow, tod, Wc, bias, out);
}